// Round 1
// baseline (1165.650 us; speedup 1.0000x reference)
//
#include <hip/hip_runtime.h>
#include <hip/hip_bf16.h>

#define NN 10000
#define EE 128000
#define ETOT 138000
#define DD 256
#define DIN 64

// ---------------- small utility kernels ----------------

__global__ void transpose_k(const float* __restrict__ W, float* __restrict__ WT, int R, int C) {
    int idx = blockIdx.x * 256 + threadIdx.x;
    if (idx >= R * C) return;
    int r = idx / C, c = idx % C;
    WT[c * R + r] = W[idx];
}

__global__ void deg_k(const int* __restrict__ ei, int* __restrict__ deg, int E, int Etot) {
    int e = blockIdx.x * 256 + threadIdx.x;
    if (e >= Etot) return;
    int dn = (e < E) ? ei[E + e] : (e - E);
    atomicAdd(&deg[dn], 1);
}

__global__ __launch_bounds__(1024) void scan_k(const int* __restrict__ deg, int* __restrict__ offs,
                                               int* __restrict__ cursor, int Nn) {
    __shared__ int ps[1024];
    int t = threadIdx.x;
    int chunk = (Nn + 1023) >> 10;
    int i0 = t * chunk;
    int local = 0;
    for (int i = 0; i < chunk; i++) {
        int idx = i0 + i;
        if (idx < Nn) local += deg[idx];
    }
    ps[t] = local;
    __syncthreads();
    for (int off = 1; off < 1024; off <<= 1) {
        int v = 0;
        if (t >= off) v = ps[t - off];
        __syncthreads();
        if (t >= off) ps[t] += v;
        __syncthreads();
    }
    int run = ps[t] - local;  // exclusive
    for (int i = 0; i < chunk; i++) {
        int idx = i0 + i;
        if (idx < Nn) {
            offs[idx] = run;
            cursor[idx] = run;
            run += deg[idx];
        }
    }
}

__global__ void csr_fill_k(const int* __restrict__ ei, int* __restrict__ cursor,
                           int* __restrict__ csr_eid, int* __restrict__ csr_src, int E, int Etot) {
    int e = blockIdx.x * 256 + threadIdx.x;
    if (e >= Etot) return;
    int s, dn;
    if (e < E) { s = ei[e]; dn = ei[E + e]; }
    else { s = dn = e - E; }
    int pos = atomicAdd(&cursor[dn], 1);
    csr_eid[pos] = e;
    csr_src[pos] = s;
}

// ---------------- GAT score path ----------------

// per node: a_src[n][h], a_dst[n][h] = 0.25 * sum_v sum_f lrelu(h[v,n,h,f]) * att_{src,dst}[h][f]
__global__ __launch_bounds__(256) void att_scores_k(const float* __restrict__ h, const float* __restrict__ att,
                                                    float* __restrict__ asrc, float* __restrict__ adst, int Nn) {
    int n = blockIdx.x, t = threadIdx.x, hd = t >> 6, f = t & 63;
    float ws_ = att[hd * 128 + f];
    float wd_ = att[hd * 128 + 64 + f];
    float s = 0.f, d = 0.f;
    for (int v = 0; v < 4; v++) {
        float xv = h[((long)v * Nn + n) * DD + t];
        float xl = xv > 0.f ? xv : 0.2f * xv;
        s += xl * ws_;
        d += xl * wd_;
    }
    for (int o = 32; o; o >>= 1) {
        s += __shfl_down(s, o, 64);
        d += __shfl_down(d, o, 64);
    }
    if ((t & 63) == 0) {
        asrc[n * 4 + hd] = s * 0.25f;
        adst[n * 4 + hd] = d * 0.25f;
    }
}

__global__ void edge_scores_k(const int* __restrict__ ei, const float* __restrict__ asrc,
                              const float* __restrict__ adst, float* __restrict__ sc, int E, int Etot) {
    int idx = blockIdx.x * 256 + threadIdx.x;
    if (idx >= Etot * 4) return;
    int e = idx >> 2, hd = idx & 3;
    int s, dn;
    if (e < E) { s = ei[e]; dn = ei[E + e]; }
    else { s = dn = e - E; }
    sc[idx] = asrc[s * 4 + hd] + adst[dn * 4 + hd];
}

__global__ __launch_bounds__(256) void head_max1_k(const float* __restrict__ sc, float* __restrict__ pmax, int total) {
    int t = threadIdx.x;
    int gid = blockIdx.x * 256 + t;
    int stride = gridDim.x * 256;  // multiple of 4 -> hd constant per thread
    float m = -3.4e38f;
    for (int idx = gid; idx < total; idx += stride) m = fmaxf(m, sc[idx]);
    __shared__ float lds[256];
    lds[t] = m;
    __syncthreads();
    if (t < 4) {
        float r = -3.4e38f;
        for (int j = t; j < 256; j += 4) r = fmaxf(r, lds[j]);
        pmax[blockIdx.x * 4 + t] = r;
    }
}

__global__ void head_max2_k(const float* __restrict__ pmax, float* __restrict__ hmax, int nblocks) {
    int t = threadIdx.x;
    if (t < 4) {
        float r = -3.4e38f;
        for (int b = 0; b < nblocks; b++) r = fmaxf(r, pmax[b * 4 + t]);
        hmax[t] = r;
    }
}

__global__ __launch_bounds__(256) void exp_sum_k(float* __restrict__ sc, const float* __restrict__ hmax,
                                                 float* __restrict__ hsum, int total) {
    __shared__ float ls[4];
    int t = threadIdx.x;
    if (t < 4) ls[t] = 0.f;
    __syncthreads();
    int idx = blockIdx.x * 256 + t;
    if (idx < total) {
        int hd = idx & 3;
        float w = expf(sc[idx] - hmax[hd]);
        sc[idx] = w;
        atomicAdd(&ls[hd], w);
    }
    __syncthreads();
    if (t < 4) atomicAdd(&hsum[t], ls[t]);
}

// gather aggregation: agg[v][n][d] = (1/hsum[hd]) * sum_{e in in(n)} wts[e][hd] * h[v][src(e)][d]
__global__ __launch_bounds__(256) void agg_k(const float* __restrict__ h, const float* __restrict__ wts,
                                             const int* __restrict__ offs, const int* __restrict__ deg,
                                             const int* __restrict__ csr_eid, const int* __restrict__ csr_src,
                                             const float* __restrict__ hsum, float* __restrict__ agg, int Nn) {
    int n = blockIdx.x, t = threadIdx.x, hd = t >> 6;
    float inv = 1.0f / hsum[hd];
    int o0 = offs[n], dg = deg[n];
    float a0 = 0.f, a1 = 0.f, a2 = 0.f, a3 = 0.f;
    const long vs = (long)Nn * DD;
    for (int p = 0; p < dg; p++) {
        int e = csr_eid[o0 + p];
        int s = csr_src[o0 + p];
        float w = wts[e * 4 + hd];
        const float* hp = h + (long)s * DD + t;
        a0 += w * hp[0];
        a1 += w * hp[vs];
        a2 += w * hp[2 * vs];
        a3 += w * hp[3 * vs];
    }
    long ob = (long)n * DD + t;
    agg[ob] = a0 * inv;
    agg[vs + ob] = a1 * inv;
    agg[2 * vs + ob] = a2 * inv;
    agg[3 * vs + ob] = a3 * inv;
}

// ---------------- generic fp32 NT GEMM: C[m][col] = sum_k A[m][k]*B[col][k] (+bias) ----------------
// AMODE 0: A row m identity. AMODE 1: A phys row = (m&3)*Nnodes + nodeBase + (m>>2)  (view-interleaved gather)
// CMODE 0: C row m identity. CMODE 1: C phys row = (m&3)*Nnodes + nodeBase + (m>>2)  (scatter to [v][n][d])
// ACT 0: none, 1: elu
template <int AMODE, int CMODE, int ACT>
__global__ __launch_bounds__(256) void gemm_nt(const float* __restrict__ A, const float* __restrict__ B,
                                               const float* __restrict__ b1, const float* __restrict__ b2,
                                               float* __restrict__ C, int M, int Ncols, int K,
                                               int Nnodes, int nodeBase) {
    const int BM = 128, BN = 64, BK = 16;
    __shared__ float As[BK][BM + 4];
    __shared__ float Bs[BK][BN + 4];
    int t = threadIdx.x;
    int tx = t & 15, ty = t >> 4;
    int row0 = blockIdx.y * BM;
    int col0 = blockIdx.x * BN;

    float acc[8][4];
#pragma unroll
    for (int i = 0; i < 8; i++)
#pragma unroll
        for (int j = 0; j < 4; j++) acc[i][j] = 0.f;

    int arow_l = t >> 1;        // 0..127
    int akk0 = (t & 1) * 8;     // 0 or 8
    int am = row0 + arow_l;
    bool avalid = am < M;
    long aphys;
    if (AMODE == 0) aphys = (long)am;
    else aphys = (long)(am & 3) * Nnodes + nodeBase + (am >> 2);
    const float* Aptr = A + aphys * K + akk0;

    int bcol_l = t >> 2;        // 0..63
    int bkk0 = (t & 3) * 4;     // 0,4,8,12
    const float* Bptr = B + (long)(col0 + bcol_l) * K + bkk0;

    for (int k0 = 0; k0 < K; k0 += BK) {
        float4 a0 = make_float4(0.f, 0.f, 0.f, 0.f), a1 = a0;
        if (avalid) {
            a0 = *(const float4*)(Aptr + k0);
            a1 = *(const float4*)(Aptr + k0 + 4);
        }
        float4 b0 = *(const float4*)(Bptr + k0);
        As[akk0 + 0][arow_l] = a0.x;
        As[akk0 + 1][arow_l] = a0.y;
        As[akk0 + 2][arow_l] = a0.z;
        As[akk0 + 3][arow_l] = a0.w;
        As[akk0 + 4][arow_l] = a1.x;
        As[akk0 + 5][arow_l] = a1.y;
        As[akk0 + 6][arow_l] = a1.z;
        As[akk0 + 7][arow_l] = a1.w;
        Bs[bkk0 + 0][bcol_l] = b0.x;
        Bs[bkk0 + 1][bcol_l] = b0.y;
        Bs[bkk0 + 2][bcol_l] = b0.z;
        Bs[bkk0 + 3][bcol_l] = b0.w;
        __syncthreads();
#pragma unroll
        for (int kk = 0; kk < BK; kk++) {
            float ar[8], br[4];
#pragma unroll
            for (int i = 0; i < 8; i++) ar[i] = As[kk][ty * 8 + i];
#pragma unroll
            for (int j = 0; j < 4; j++) br[j] = Bs[kk][tx * 4 + j];
#pragma unroll
            for (int i = 0; i < 8; i++)
#pragma unroll
                for (int j = 0; j < 4; j++) acc[i][j] += ar[i] * br[j];
        }
        __syncthreads();
    }

#pragma unroll
    for (int i = 0; i < 8; i++) {
        int m = row0 + ty * 8 + i;
        if (m >= M) continue;
        long cphys;
        if (CMODE == 0) cphys = (long)m;
        else cphys = (long)(m & 3) * Nnodes + nodeBase + (m >> 2);
#pragma unroll
        for (int j = 0; j < 4; j++) {
            int col = col0 + tx * 4 + j;
            float v = acc[i][j];
            if (b1) v += b1[col];
            if (b2) v += b2[col];
            if (ACT == 1) v = v > 0.f ? v : expm1f(v);
            C[cphys * Ncols + col] = v;
        }
    }
}

// ---------------- per-node 4-token MHA ----------------
// qkv: [localNode][v][768] ; o: [localNode*4+v][256]
__global__ __launch_bounds__(256) void attn_k(const float* __restrict__ qkv, float* __restrict__ o, int chunkN) {
    __shared__ float s[3072];
    __shared__ float lg[64];  // [(vq*4+hd)*4 + vk]
    int ln = blockIdx.x;
    int t = threadIdx.x;
    const float* base = qkv + (long)ln * 3072;
    for (int i = t; i < 3072; i += 256) s[i] = base[i];
    __syncthreads();
    if (t < 64) {
        int vq = t >> 4, vk = (t >> 2) & 3, hd = t & 3;
        const float* qp = s + vq * 768 + hd * 64;
        const float* kp = s + vk * 768 + 256 + hd * 64;
        float l = 0.f;
        for (int f = 0; f < 64; f++) l += qp[f] * kp[f];
        lg[(vq * 4 + hd) * 4 + vk] = l * 0.125f;  // 1/sqrt(64)
    }
    __syncthreads();
    if (t < 16) {
        int vq = t >> 2, hd = t & 3;
        float* p = lg + (vq * 4 + hd) * 4;
        float mx = fmaxf(fmaxf(p[0], p[1]), fmaxf(p[2], p[3]));
        float e0 = expf(p[0] - mx), e1 = expf(p[1] - mx), e2 = expf(p[2] - mx), e3 = expf(p[3] - mx);
        float inv = 1.f / (e0 + e1 + e2 + e3);
        p[0] = e0 * inv;
        p[1] = e1 * inv;
        p[2] = e2 * inv;
        p[3] = e3 * inv;
    }
    __syncthreads();
    int hd = t >> 6;
    for (int vq = 0; vq < 4; vq++) {
        const float* a = lg + (vq * 4 + hd) * 4;
        float r = a[0] * s[0 * 768 + 512 + t] + a[1] * s[1 * 768 + 512 + t] +
                  a[2] * s[2 * 768 + 512 + t] + a[3] * s[3 * 768 + 512 + t];
        o[((long)(ln * 4 + vq)) * 256 + t] = r;
    }
}

// ---------------- launcher ----------------

extern "C" void kernel_launch(void* const* d_in, const int* in_sizes, int n_in,
                              void* d_out, int out_size, void* d_ws, size_t ws_size,
                              hipStream_t stream) {
    const float* x = (const float*)d_in[0];
    const int* ei = (const int*)d_in[1];
    const float* W1 = (const float*)d_in[2];
    const float* att1 = (const float*)d_in[3];
    const float* qkv_w1 = (const float*)d_in[4];
    const float* qkv_b1 = (const float*)d_in[5];
    const float* out_w1 = (const float*)d_in[6];
    const float* out_b1 = (const float*)d_in[7];
    const float* bias1 = (const float*)d_in[8];
    const float* W2 = (const float*)d_in[9];
    const float* att2 = (const float*)d_in[10];
    const float* qkv_w2 = (const float*)d_in[11];
    const float* qkv_b2 = (const float*)d_in[12];
    const float* out_w2 = (const float*)d_in[13];
    const float* out_b2 = (const float*)d_in[14];
    const float* bias2 = (const float*)d_in[15];
    float* out = (float*)d_out;

    const int Nn = NN, E = EE, Etot = ETOT;

    char* wsB = (char*)d_ws;
    size_t off = 0;
    auto alloc = [&](size_t bytes) -> void* {
        void* p = wsB + off;
        off += (bytes + 255) & ~(size_t)255;
        return p;
    };
    float* W1T = (float*)alloc((size_t)256 * 64 * 4);
    float* W2T = (float*)alloc((size_t)256 * 256 * 4);
    float* hbuf = (float*)alloc((size_t)4 * Nn * DD * 4);
    float* aggb = (float*)alloc((size_t)4 * Nn * DD * 4);
    float* asrc = (float*)alloc((size_t)Nn * 4 * 4);
    float* adst = (float*)alloc((size_t)Nn * 4 * 4);
    float* wts = (float*)alloc((size_t)Etot * 4 * 4);
    float* hmax = (float*)alloc(4 * 4);
    float* hsum = (float*)alloc(4 * 4);
    float* pmax = (float*)alloc((size_t)256 * 4 * 4);
    int* deg = (int*)alloc((size_t)Nn * 4);
    int* offs = (int*)alloc((size_t)Nn * 4);
    int* cursor = (int*)alloc((size_t)Nn * 4);
    int* csr_eid = (int*)alloc((size_t)Etot * 4);
    int* csr_src = (int*)alloc((size_t)Etot * 4);

    // choose node-chunking for the qkv/o buffers based on available workspace
    auto aligned = [](size_t b) { return (b + 255) & ~(size_t)255; };
    int nchunks = 40;
    {
        const int cands[8] = {1, 2, 4, 5, 8, 10, 20, 40};
        for (int ci = 0; ci < 8; ci++) {
            int cN = Nn / cands[ci];
            size_t need = off + aligned((size_t)cN * 4 * 768 * 4) + aligned((size_t)cN * 4 * 256 * 4);
            if (need <= ws_size) { nchunks = cands[ci]; break; }
        }
    }
    int chunkN = Nn / nchunks;
    float* qkvb = (float*)alloc((size_t)chunkN * 4 * 768 * 4);
    float* ob = (float*)alloc((size_t)chunkN * 4 * 256 * 4);

    // --- one-time (per call) prep: weight transposes + CSR over dst ---
    transpose_k<<<(64 * 256 + 255) / 256, 256, 0, stream>>>(W1, W1T, 64, 256);
    transpose_k<<<(256 * 256 + 255) / 256, 256, 0, stream>>>(W2, W2T, 256, 256);
    hipMemsetAsync(deg, 0, Nn * sizeof(int), stream);
    deg_k<<<(Etot + 255) / 256, 256, 0, stream>>>(ei, deg, E, Etot);
    scan_k<<<1, 1024, 0, stream>>>(deg, offs, cursor, Nn);
    csr_fill_k<<<(Etot + 255) / 256, 256, 0, stream>>>(ei, cursor, csr_eid, csr_src, E, Etot);

    auto layer = [&](const float* xin, int K, const float* WT, const float* att,
                     const float* qkv_w, const float* qkv_b, const float* out_w,
                     const float* out_b, const float* bias, float* outbuf, bool elu) {
        // h = xin @ W  -> hbuf [v][n][256]
        {
            dim3 g(256 / 64, (40000 + 127) / 128);
            gemm_nt<0, 0, 0><<<g, 256, 0, stream>>>(xin, WT, nullptr, nullptr, hbuf, 40000, 256, K, Nn, 0);
        }
        att_scores_k<<<Nn, 256, 0, stream>>>(hbuf, att, asrc, adst, Nn);
        edge_scores_k<<<(Etot * 4 + 255) / 256, 256, 0, stream>>>(ei, asrc, adst, wts, E, Etot);
        head_max1_k<<<256, 256, 0, stream>>>(wts, pmax, Etot * 4);
        head_max2_k<<<1, 64, 0, stream>>>(pmax, hmax, 256);
        hipMemsetAsync(hsum, 0, 16, stream);
        exp_sum_k<<<(Etot * 4 + 255) / 256, 256, 0, stream>>>(wts, hmax, hsum, Etot * 4);
        agg_k<<<Nn, 256, 0, stream>>>(hbuf, wts, offs, deg, csr_eid, csr_src, hsum, aggb, Nn);
        // chunked MHA over views
        for (int c = 0; c < nchunks; c++) {
            int nb = c * chunkN;
            int Mc = chunkN * 4;
            dim3 gq(768 / 64, (Mc + 127) / 128);
            gemm_nt<1, 0, 0><<<gq, 256, 0, stream>>>(aggb, qkv_w, qkv_b, nullptr, qkvb, Mc, 768, 256, Nn, nb);
            attn_k<<<chunkN, 256, 0, stream>>>(qkvb, ob, chunkN);
            dim3 go(256 / 64, (Mc + 127) / 128);
            if (elu)
                gemm_nt<0, 1, 1><<<go, 256, 0, stream>>>(ob, out_w, out_b, bias, outbuf, Mc, 256, 256, Nn, nb);
            else
                gemm_nt<0, 1, 0><<<go, 256, 0, stream>>>(ob, out_w, out_b, bias, outbuf, Mc, 256, 256, Nn, nb);
        }
    };

    // layer 1: input x (K=64), output (with elu) -> d_out acts as h1
    layer(x, DIN, W1T, att1, qkv_w1, qkv_b1, out_w1, out_b1, bias1, out, true);
    // layer 2: input h1 (=d_out, fully consumed by the first GEMM), final output -> d_out
    layer(out, DD, W2T, att2, qkv_w2, qkv_b2, out_w2, out_b2, bias2, out, false);
}

// Round 2
// 730.792 us; speedup vs baseline: 1.5951x; 1.5951x over previous
//
#include <hip/hip_runtime.h>

#define NN 10000
#define EE 128000
#define ETOT 138000
#define DD 256
#define DIN 64

typedef unsigned short u16;
typedef __attribute__((ext_vector_type(8))) short short8v;
typedef __attribute__((ext_vector_type(4))) float f32x4;

__device__ inline u16 f2bf(float f) {
    union { float f; unsigned u; } a; a.f = f;
    unsigned r = a.u + 0x7fffu + ((a.u >> 16) & 1u);
    return (u16)(r >> 16);
}
__device__ inline float bf2f(u16 b) {
    union { unsigned u; float f; } a; a.u = ((unsigned)b) << 16;
    return a.f;
}

// ---------------- weight split kernels ----------------

// src already NT ([col][k]) -> elementwise split
__global__ void split_k(const float* __restrict__ W, u16* __restrict__ H, u16* __restrict__ L, int total) {
    int i = blockIdx.x * 256 + threadIdx.x;
    if (i >= total) return;
    float f = W[i];
    u16 h = f2bf(f);
    H[i] = h;
    L[i] = f2bf(f - bf2f(h));
}

// src [R][C] (k-major) -> dst [C][R] NT, split
__global__ void transpose_split_k(const float* __restrict__ W, u16* __restrict__ H, u16* __restrict__ L,
                                  int R, int C) {
    int idx = blockIdx.x * 256 + threadIdx.x;
    if (idx >= R * C) return;
    int r = idx / C, c = idx % C;
    float f = W[idx];
    u16 h = f2bf(f);
    H[c * R + r] = h;
    L[c * R + r] = f2bf(f - bf2f(h));
}

// ---------------- CSR build ----------------

__global__ void deg_k(const int* __restrict__ ei, int* __restrict__ deg, int E, int Etot) {
    int e = blockIdx.x * 256 + threadIdx.x;
    if (e >= Etot) return;
    int dn = (e < E) ? ei[E + e] : (e - E);
    atomicAdd(&deg[dn], 1);
}

__global__ __launch_bounds__(1024) void scan_k(const int* __restrict__ deg, int* __restrict__ offs,
                                               int* __restrict__ cursor, int Nn) {
    __shared__ int ps[1024];
    int t = threadIdx.x;
    int chunk = (Nn + 1023) >> 10;
    int i0 = t * chunk;
    int local = 0;
    for (int i = 0; i < chunk; i++) {
        int idx = i0 + i;
        if (idx < Nn) local += deg[idx];
    }
    ps[t] = local;
    __syncthreads();
    for (int off = 1; off < 1024; off <<= 1) {
        int v = 0;
        if (t >= off) v = ps[t - off];
        __syncthreads();
        if (t >= off) ps[t] += v;
        __syncthreads();
    }
    int run = ps[t] - local;  // exclusive
    for (int i = 0; i < chunk; i++) {
        int idx = i0 + i;
        if (idx < Nn) {
            offs[idx] = run;
            cursor[idx] = run;
            run += deg[idx];
        }
    }
}

__global__ void csr_fill_k(const int* __restrict__ ei, int* __restrict__ cursor,
                           int* __restrict__ csr_eid, int* __restrict__ csr_src, int E, int Etot) {
    int e = blockIdx.x * 256 + threadIdx.x;
    if (e >= Etot) return;
    int s, dn;
    if (e < E) { s = ei[e]; dn = ei[E + e]; }
    else { s = dn = e - E; }
    int pos = atomicAdd(&cursor[dn], 1);
    csr_eid[pos] = e;
    csr_src[pos] = s;
}

// ---------------- GAT score path ----------------

__global__ __launch_bounds__(256) void att_scores_k(const float* __restrict__ h, const float* __restrict__ att,
                                                    float* __restrict__ asrc, float* __restrict__ adst, int Nn) {
    int n = blockIdx.x, t = threadIdx.x, hd = t >> 6;
    int f = t & 63;
    float ws_ = att[hd * 128 + f];
    float wd_ = att[hd * 128 + 64 + f];
    float s = 0.f, d = 0.f;
    for (int v = 0; v < 4; v++) {
        float xv = h[((long)v * Nn + n) * DD + t];
        float xl = xv > 0.f ? xv : 0.2f * xv;
        s += xl * ws_;
        d += xl * wd_;
    }
    for (int o = 32; o; o >>= 1) {
        s += __shfl_down(s, o, 64);
        d += __shfl_down(d, o, 64);
    }
    if ((t & 63) == 0) {
        asrc[n * 4 + hd] = s * 0.25f;
        adst[n * 4 + hd] = d * 0.25f;
    }
}

__global__ void edge_scores_k(const int* __restrict__ ei, const float* __restrict__ asrc,
                              const float* __restrict__ adst, float* __restrict__ sc, int E, int Etot) {
    int idx = blockIdx.x * 256 + threadIdx.x;
    if (idx >= Etot * 4) return;
    int e = idx >> 2, hd = idx & 3;
    int s, dn;
    if (e < E) { s = ei[e]; dn = ei[E + e]; }
    else { s = dn = e - E; }
    sc[idx] = asrc[s * 4 + hd] + adst[dn * 4 + hd];
}

__global__ __launch_bounds__(256) void head_max1_k(const float* __restrict__ sc, float* __restrict__ pmax, int total) {
    int t = threadIdx.x;
    int gid = blockIdx.x * 256 + t;
    int stride = gridDim.x * 256;
    float m = -3.4e38f;
    for (int idx = gid; idx < total; idx += stride) m = fmaxf(m, sc[idx]);
    __shared__ float lds[256];
    lds[t] = m;
    __syncthreads();
    if (t < 4) {
        float r = -3.4e38f;
        for (int j = t; j < 256; j += 4) r = fmaxf(r, lds[j]);
        pmax[blockIdx.x * 4 + t] = r;
    }
}

__global__ void head_max2_k(const float* __restrict__ pmax, float* __restrict__ hmax, int nblocks) {
    int t = threadIdx.x;
    if (t < 4) {
        float r = -3.4e38f;
        for (int b = 0; b < nblocks; b++) r = fmaxf(r, pmax[b * 4 + t]);
        hmax[t] = r;
    }
}

__global__ __launch_bounds__(256) void exp_sum_k(float* __restrict__ sc, const float* __restrict__ hmax,
                                                 float* __restrict__ hsum, int total) {
    __shared__ float ls[4];
    int t = threadIdx.x;
    if (t < 4) ls[t] = 0.f;
    __syncthreads();
    int idx = blockIdx.x * 256 + t;
    if (idx < total) {
        int hd = idx & 3;
        float w = expf(sc[idx] - hmax[hd]);
        sc[idx] = w;
        atomicAdd(&ls[hd], w);
    }
    __syncthreads();
    if (t < 4) atomicAdd(&hsum[t], ls[t]);
}

__global__ __launch_bounds__(256) void agg_k(const float* __restrict__ h, const float* __restrict__ wts,
                                             const int* __restrict__ offs, const int* __restrict__ deg,
                                             const int* __restrict__ csr_eid, const int* __restrict__ csr_src,
                                             const float* __restrict__ hsum, float* __restrict__ agg, int Nn) {
    int n = blockIdx.x, t = threadIdx.x, hd = t >> 6;
    float inv = 1.0f / hsum[hd];
    int o0 = offs[n], dg = deg[n];
    float a0 = 0.f, a1 = 0.f, a2 = 0.f, a3 = 0.f;
    const long vs = (long)Nn * DD;
    for (int p = 0; p < dg; p++) {
        int e = csr_eid[o0 + p];
        int s = csr_src[o0 + p];
        float w = wts[e * 4 + hd];
        const float* hp = h + (long)s * DD + t;
        a0 += w * hp[0];
        a1 += w * hp[vs];
        a2 += w * hp[2 * vs];
        a3 += w * hp[3 * vs];
    }
    long ob = (long)n * DD + t;
    agg[ob] = a0 * inv;
    agg[vs + ob] = a1 * inv;
    agg[2 * vs + ob] = a2 * inv;
    agg[3 * vs + ob] = a3 * inv;
}

// ---------------- split-bf16 MFMA NT GEMM ----------------
// C[m][col] = sum_k A[m][k] * B[col][k] (+bias), A fp32, B pre-split bf16 hi/lo NT.
// AMODE/CMODE 1: phys row = (m&3)*Nnodes + nodeBase + (m>>2). ACT 1: elu.
template <int AMODE, int CMODE, int ACT>
__global__ __launch_bounds__(256) void gemm_split_bf16(
    const float* __restrict__ A, const u16* __restrict__ BHp, const u16* __restrict__ BLp,
    const float* __restrict__ b1, const float* __restrict__ b2,
    float* __restrict__ C, int M, int Ncols, int K, int Nnodes, int nodeBase) {
    __shared__ u16 AhS[128 * 32], AlS[128 * 32], BhS[128 * 32], BlS[128 * 32];
    int t = threadIdx.x;
    int row0 = blockIdx.y * 128, col0 = blockIdx.x * 128;
    int lane = t & 63, wv = t >> 6;
    int wr = wv >> 1, wc = wv & 1;
    int lm = lane & 15, lk = lane >> 4;
    const int gsw = (lk ^ ((lm >> 1) & 3)) * 8;  // swizzled k-group offset (elems)

    f32x4 acc[4][4];
#pragma unroll
    for (int i = 0; i < 4; i++)
#pragma unroll
        for (int j = 0; j < 4; j++) acc[i][j] = (f32x4)(0.f);

    for (int k0 = 0; k0 < K; k0 += 32) {
        // ---- B staging: bf16 hi/lo from global, swizzled ds_write ----
#pragma unroll
        for (int it = 0; it < 2; it++) {
            int idx = t + it * 256;            // 0..511
            int c = idx >> 2, gp = idx & 3;
            int klog = k0 + ((gp ^ ((c >> 1) & 3)) << 3);
            long src = (long)(col0 + c) * K + klog;
            short8v bh = *(const short8v*)&BHp[src];
            short8v bl = *(const short8v*)&BLp[src];
            *(short8v*)&BhS[c * 32 + gp * 8] = bh;
            *(short8v*)&BlS[c * 32 + gp * 8] = bl;
        }
        // ---- A staging: fp32 -> split bf16 hi/lo, swizzled ds_write ----
#pragma unroll
        for (int it = 0; it < 2; it++) {
            int idx = t + it * 256;
            int m = idx >> 2, kg = idx & 3;
            int am = row0 + m;
            long aphys = (AMODE == 0) ? (long)am
                                      : (long)(am & 3) * Nnodes + nodeBase + (am >> 2);
            float4 f0 = make_float4(0.f, 0.f, 0.f, 0.f), f1 = f0;
            if (am < M) {
                const float* ap = A + aphys * K + k0 + kg * 8;
                f0 = *(const float4*)ap;
                f1 = *(const float4*)(ap + 4);
            }
            union { short8v v; u16 u[8]; } hv, lv;
            float fs[8] = {f0.x, f0.y, f0.z, f0.w, f1.x, f1.y, f1.z, f1.w};
#pragma unroll
            for (int j2 = 0; j2 < 8; j2++) {
                u16 hb = f2bf(fs[j2]);
                hv.u[j2] = hb;
                lv.u[j2] = f2bf(fs[j2] - bf2f(hb));
            }
            int gp = kg ^ ((m >> 1) & 3);
            *(short8v*)&AhS[m * 32 + gp * 8] = hv.v;
            *(short8v*)&AlS[m * 32 + gp * 8] = lv.v;
        }
        __syncthreads();
        // ---- fragments + 48 MFMA ----
        short8v afh[4], afl[4], bfh[4], bfl[4];
#pragma unroll
        for (int i = 0; i < 4; i++) {
            int am_l = wr * 64 + i * 16 + lm;
            afh[i] = *(const short8v*)&AhS[am_l * 32 + gsw];
            afl[i] = *(const short8v*)&AlS[am_l * 32 + gsw];
            int bc_l = wc * 64 + i * 16 + lm;
            bfh[i] = *(const short8v*)&BhS[bc_l * 32 + gsw];
            bfl[i] = *(const short8v*)&BlS[bc_l * 32 + gsw];
        }
#pragma unroll
        for (int i = 0; i < 4; i++)
#pragma unroll
            for (int j = 0; j < 4; j++) {
                acc[i][j] = __builtin_amdgcn_mfma_f32_16x16x32_bf16(afh[i], bfh[j], acc[i][j], 0, 0, 0);
                acc[i][j] = __builtin_amdgcn_mfma_f32_16x16x32_bf16(afl[i], bfh[j], acc[i][j], 0, 0, 0);
                acc[i][j] = __builtin_amdgcn_mfma_f32_16x16x32_bf16(afh[i], bfl[j], acc[i][j], 0, 0, 0);
            }
        __syncthreads();
    }

    // ---- epilogue: C/D layout col=lane&15, row=(lane>>4)*4+r ----
#pragma unroll
    for (int i = 0; i < 4; i++) {
        int rowb = row0 + wr * 64 + i * 16 + lk * 4;
#pragma unroll
        for (int j = 0; j < 4; j++) {
            int col = col0 + wc * 64 + j * 16 + lm;
            float bb = (b1 ? b1[col] : 0.f) + (b2 ? b2[col] : 0.f);
#pragma unroll
            for (int r = 0; r < 4; r++) {
                int mrow = rowb + r;
                if (mrow >= M) continue;
                long cphys = (CMODE == 0) ? (long)mrow
                                          : (long)(mrow & 3) * Nnodes + nodeBase + (mrow >> 2);
                float v = acc[i][j][r] + bb;
                if (ACT == 1) v = v > 0.f ? v : expm1f(v);
                C[cphys * Ncols + col] = v;
            }
        }
    }
}

// ---------------- per-node 4-token MHA ----------------
__global__ __launch_bounds__(256) void attn_k(const float* __restrict__ qkv, float* __restrict__ o, int chunkN) {
    __shared__ float s[3072];
    __shared__ float lg[64];
    int ln = blockIdx.x;
    int t = threadIdx.x;
    const float* base = qkv + (long)ln * 3072;
    for (int i = t; i < 3072; i += 256) s[i] = base[i];
    __syncthreads();
    if (t < 64) {
        int vq = t >> 4, vk = (t >> 2) & 3, hd = t & 3;
        const float* qp = s + vq * 768 + hd * 64;
        const float* kp = s + vk * 768 + 256 + hd * 64;
        float l = 0.f;
        for (int f = 0; f < 64; f++) l += qp[f] * kp[f];
        lg[(vq * 4 + hd) * 4 + vk] = l * 0.125f;
    }
    __syncthreads();
    if (t < 16) {
        int vq = t >> 2, hd = t & 3;
        float* p = lg + (vq * 4 + hd) * 4;
        float mx = fmaxf(fmaxf(p[0], p[1]), fmaxf(p[2], p[3]));
        float e0 = expf(p[0] - mx), e1 = expf(p[1] - mx), e2 = expf(p[2] - mx), e3 = expf(p[3] - mx);
        float inv = 1.f / (e0 + e1 + e2 + e3);
        p[0] = e0 * inv; p[1] = e1 * inv; p[2] = e2 * inv; p[3] = e3 * inv;
    }
    __syncthreads();
    int hd = t >> 6;
    for (int vq = 0; vq < 4; vq++) {
        const float* a = lg + (vq * 4 + hd) * 4;
        float r = a[0] * s[0 * 768 + 512 + t] + a[1] * s[1 * 768 + 512 + t] +
                  a[2] * s[2 * 768 + 512 + t] + a[3] * s[3 * 768 + 512 + t];
        o[((long)(ln * 4 + vq)) * 256 + t] = r;
    }
}

// ---------------- launcher ----------------

extern "C" void kernel_launch(void* const* d_in, const int* in_sizes, int n_in,
                              void* d_out, int out_size, void* d_ws, size_t ws_size,
                              hipStream_t stream) {
    const float* x = (const float*)d_in[0];
    const int* ei = (const int*)d_in[1];
    const float* W1 = (const float*)d_in[2];
    const float* att1 = (const float*)d_in[3];
    const float* qkv_w1 = (const float*)d_in[4];
    const float* qkv_b1 = (const float*)d_in[5];
    const float* out_w1 = (const float*)d_in[6];
    const float* out_b1 = (const float*)d_in[7];
    const float* bias1 = (const float*)d_in[8];
    const float* W2 = (const float*)d_in[9];
    const float* att2 = (const float*)d_in[10];
    const float* qkv_w2 = (const float*)d_in[11];
    const float* qkv_b2 = (const float*)d_in[12];
    const float* out_w2 = (const float*)d_in[13];
    const float* out_b2 = (const float*)d_in[14];
    const float* bias2 = (const float*)d_in[15];
    float* out = (float*)d_out;

    const int Nn = NN, E = EE, Etot = ETOT;

    char* wsB = (char*)d_ws;
    size_t off = 0;
    auto alloc = [&](size_t bytes) -> void* {
        void* p = wsB + off;
        off += (bytes + 255) & ~(size_t)255;
        return p;
    };
    u16* W1TH = (u16*)alloc((size_t)256 * 64 * 2);
    u16* W1TL = (u16*)alloc((size_t)256 * 64 * 2);
    u16* W2TH = (u16*)alloc((size_t)256 * 256 * 2);
    u16* W2TL = (u16*)alloc((size_t)256 * 256 * 2);
    u16* qw1H = (u16*)alloc((size_t)768 * 256 * 2);
    u16* qw1L = (u16*)alloc((size_t)768 * 256 * 2);
    u16* qw2H = (u16*)alloc((size_t)768 * 256 * 2);
    u16* qw2L = (u16*)alloc((size_t)768 * 256 * 2);
    u16* ow1H = (u16*)alloc((size_t)256 * 256 * 2);
    u16* ow1L = (u16*)alloc((size_t)256 * 256 * 2);
    u16* ow2H = (u16*)alloc((size_t)256 * 256 * 2);
    u16* ow2L = (u16*)alloc((size_t)256 * 256 * 2);
    float* hbuf = (float*)alloc((size_t)4 * Nn * DD * 4);
    float* aggb = (float*)alloc((size_t)4 * Nn * DD * 4);
    float* asrc = (float*)alloc((size_t)Nn * 4 * 4);
    float* adst = (float*)alloc((size_t)Nn * 4 * 4);
    float* wts = (float*)alloc((size_t)Etot * 4 * 4);
    float* hmax = (float*)alloc(4 * 4);
    float* hsum = (float*)alloc(4 * 4);
    float* pmax = (float*)alloc((size_t)256 * 4 * 4);
    int* deg = (int*)alloc((size_t)Nn * 4);
    int* offs = (int*)alloc((size_t)Nn * 4);
    int* cursor = (int*)alloc((size_t)Nn * 4);
    int* csr_eid = (int*)alloc((size_t)Etot * 4);
    int* csr_src = (int*)alloc((size_t)Etot * 4);

    auto aligned = [](size_t b) { return (b + 255) & ~(size_t)255; };
    int nchunks = 40;
    {
        const int cands[8] = {1, 2, 4, 5, 8, 10, 20, 40};
        for (int ci = 0; ci < 8; ci++) {
            int cN = Nn / cands[ci];
            size_t need = off + aligned((size_t)cN * 4 * 768 * 4) + aligned((size_t)cN * 4 * 256 * 4);
            if (need <= ws_size) { nchunks = cands[ci]; break; }
        }
    }
    int chunkN = Nn / nchunks;
    float* qkvb = (float*)alloc((size_t)chunkN * 4 * 768 * 4);
    float* ob = (float*)alloc((size_t)chunkN * 4 * 256 * 4);

    // --- prep: weight splits + CSR ---
    transpose_split_k<<<(64 * 256 + 255) / 256, 256, 0, stream>>>(W1, W1TH, W1TL, 64, 256);
    transpose_split_k<<<(256 * 256 + 255) / 256, 256, 0, stream>>>(W2, W2TH, W2TL, 256, 256);
    split_k<<<(768 * 256 + 255) / 256, 256, 0, stream>>>(qkv_w1, qw1H, qw1L, 768 * 256);
    split_k<<<(768 * 256 + 255) / 256, 256, 0, stream>>>(qkv_w2, qw2H, qw2L, 768 * 256);
    split_k<<<(256 * 256 + 255) / 256, 256, 0, stream>>>(out_w1, ow1H, ow1L, 256 * 256);
    split_k<<<(256 * 256 + 255) / 256, 256, 0, stream>>>(out_w2, ow2H, ow2L, 256 * 256);
    hipMemsetAsync(deg, 0, Nn * sizeof(int), stream);
    deg_k<<<(Etot + 255) / 256, 256, 0, stream>>>(ei, deg, E, Etot);
    scan_k<<<1, 1024, 0, stream>>>(deg, offs, cursor, Nn);
    csr_fill_k<<<(Etot + 255) / 256, 256, 0, stream>>>(ei, cursor, csr_eid, csr_src, E, Etot);

    auto layer = [&](const float* xin, int K, const u16* WTH, const u16* WTL, const float* att,
                     const u16* qwH, const u16* qwL, const float* qkv_b,
                     const u16* owH, const u16* owL, const float* out_b,
                     const float* bias, float* outbuf, bool elu) {
        {
            dim3 g(256 / 128, (40000 + 127) / 128);
            gemm_split_bf16<0, 0, 0><<<g, 256, 0, stream>>>(xin, WTH, WTL, nullptr, nullptr, hbuf,
                                                            40000, 256, K, Nn, 0);
        }
        att_scores_k<<<Nn, 256, 0, stream>>>(hbuf, att, asrc, adst, Nn);
        edge_scores_k<<<(Etot * 4 + 255) / 256, 256, 0, stream>>>(ei, asrc, adst, wts, E, Etot);
        head_max1_k<<<256, 256, 0, stream>>>(wts, pmax, Etot * 4);
        head_max2_k<<<1, 64, 0, stream>>>(pmax, hmax, 256);
        hipMemsetAsync(hsum, 0, 16, stream);
        exp_sum_k<<<(Etot * 4 + 255) / 256, 256, 0, stream>>>(wts, hmax, hsum, Etot * 4);
        agg_k<<<Nn, 256, 0, stream>>>(hbuf, wts, offs, deg, csr_eid, csr_src, hsum, aggb, Nn);
        for (int c = 0; c < nchunks; c++) {
            int nb = c * chunkN;
            int Mc = chunkN * 4;
            dim3 gq(768 / 128, (Mc + 127) / 128);
            gemm_split_bf16<1, 0, 0><<<gq, 256, 0, stream>>>(aggb, qwH, qwL, qkv_b, nullptr, qkvb,
                                                             Mc, 768, 256, Nn, nb);
            attn_k<<<chunkN, 256, 0, stream>>>(qkvb, ob, chunkN);
            dim3 go(256 / 128, (Mc + 127) / 128);
            if (elu)
                gemm_split_bf16<0, 1, 1><<<go, 256, 0, stream>>>(ob, owH, owL, out_b, bias, outbuf,
                                                                 Mc, 256, 256, Nn, nb);
            else
                gemm_split_bf16<0, 1, 0><<<go, 256, 0, stream>>>(ob, owH, owL, out_b, bias, outbuf,
                                                                 Mc, 256, 256, Nn, nb);
        }
    };

    layer(x, DIN, W1TH, W1TL, att1, qw1H, qw1L, qkv_b1, ow1H, ow1L, out_b1, bias1, out, true);
    layer(out, DD, W2TH, W2TL, att2, qw2H, qw2L, qkv_b2, ow2H, ow2L, out_b2, bias2, out, false);
}